// Round 17
// baseline (7517.152 us; speedup 1.0000x reference)
//
#include <hip/hip_runtime.h>
#include <hip/hip_bf16.h>

#define Bdim 8192
#define Ddim 1024
#define Hdim 4096
#define NPOW 10
#define TAUZ 1e-5f   // hedge band: |z| < TAUZ gets relu'-weight 0.5

// Scaled-fp16-split: split arrays store SCL*value as (hi,lo) fp16.
#define SCL   512.0f
#define ISCL  (1.0f / 512.0f)
#define ISCL2 (1.0f / (512.0f * 512.0f))

typedef _Float16 f16x8 __attribute__((ext_vector_type(8)));
typedef float f32x4 __attribute__((ext_vector_type(4)));

__device__ __forceinline__ float h2f(unsigned short b) {
  _Float16 h = __builtin_bit_cast(_Float16, b);
  return (float)h;
}
__device__ __forceinline__ unsigned short f2h(float v) {
  return __builtin_bit_cast(unsigned short, (_Float16)v);
}
__device__ __forceinline__ void splitf(float v, unsigned short& hi, unsigned short& lo) {
  const float s = v * SCL;
  const _Float16 h = (_Float16)s;
  const _Float16 l = (_Float16)(s - (float)h);
  hi = __builtin_bit_cast(unsigned short, h);
  lo = __builtin_bit_cast(unsigned short, l);
}

__device__ __forceinline__ void gload_lds16(const void* g, void* l) {
  __builtin_amdgcn_global_load_lds(
      (const __attribute__((address_space(1))) void*)g,
      (__attribute__((address_space(3))) void*)l, 16, 0, 0);
}

// Bijective XCD-aware block remap (m204). Requires nwg % 8 == 0 (all our
// grids are 128 or 512 blocks). Returns swizzled flat id.
__device__ __forceinline__ unsigned xcd_swz(unsigned lid, unsigned nwg) {
  const unsigned q = nwg >> 3;
  return (lid & 7u) * q + (lid >> 3);
}

// ---------------------------------------------------------------------------
// Forward NT GEMM, split-fp16 3-term: C = sum_k A[m,k]*B[n,k] (×SCL² in acc).
// EPI 0 (z-pass):   v = C*ISCL2 + bias[n]; hedge weight 2-bit packed
//                   (u32 per 16 cols: lo16 = v>TAUZ, hi16 = |v|<=TAUZ);
//                   h = relu(v) stored split-fp16.  grid.z=1.
// EPI 5 (y-split-K): v = C*ISCL2 over K-range [z*KP,(z+1)*KP); fp32 partial.
// ---------------------------------------------------------------------------
template<int EPI>
__global__ __launch_bounds__(256, 2)
void gemm_f3(const unsigned short* __restrict__ Ah,
             const unsigned short* __restrict__ Al,
             const unsigned short* __restrict__ Bh,
             const unsigned short* __restrict__ Bl,
             int M, int N, int K, int KP,
             const float* __restrict__ bias,
             unsigned* __restrict__ wOut,
             float* __restrict__ outP,
             unsigned short* __restrict__ outH,
             unsigned short* __restrict__ outL)
{
  __shared__ __align__(16) unsigned short smem[4 * 128 * 32];
  unsigned short* sAh = smem;
  unsigned short* sAl = smem + 4096;
  unsigned short* sBh = smem + 8192;
  unsigned short* sBl = smem + 12288;

  // XCD swizzle over the flattened grid
  const unsigned gx = gridDim.x, gy = gridDim.y;
  const unsigned nwg = gx * gy * gridDim.z;
  unsigned lid = (blockIdx.z * gy + blockIdx.y) * gx + blockIdx.x;
  lid = xcd_swz(lid, nwg);
  const int bn = lid % gx;
  const int bm = (lid / gx) % gy;
  const int kz = lid / (gx * gy);

  const int t    = threadIdx.x;
  const int lane = t & 63;
  const int w    = t >> 6;
  const int wr   = (w >> 1) * 64;
  const int wc   = (w & 1) * 64;
  const int fr   = lane & 15;
  const int kg   = lane >> 4;

  f32x4 acc[4][4];
#pragma unroll
  for (int i = 0; i < 4; i++)
#pragma unroll
    for (int j = 0; j < 4; j++) acc[i][j] = (f32x4){0.f, 0.f, 0.f, 0.f};

  const int sr = t >> 2;
  const int sc = (t & 3) << 3;
  const size_t aRow  = (size_t)(bm * 128 + sr) * K;
  const size_t bRow  = (size_t)(bn * 128 + sr) * K;
  const size_t rowSk = (size_t)64 * K;
  const int ldsOff   = sr * 32 + sc;
  const int kbase    = kz * KP;

  for (int k0 = kbase; k0 < kbase + KP; k0 += 32) {
    __syncthreads();
    {
      const size_t ga = aRow + k0 + sc;
      const size_t gb = bRow + k0 + sc;
      gload_lds16(Ah + ga,         sAh + ldsOff);
      gload_lds16(Ah + ga + rowSk, sAh + 2048 + ldsOff);
      gload_lds16(Al + ga,         sAl + ldsOff);
      gload_lds16(Al + ga + rowSk, sAl + 2048 + ldsOff);
      gload_lds16(Bh + gb,         sBh + ldsOff);
      gload_lds16(Bh + gb + rowSk, sBh + 2048 + ldsOff);
      gload_lds16(Bl + gb,         sBl + ldsOff);
      gload_lds16(Bl + gb + rowSk, sBl + 2048 + ldsOff);
    }
    __syncthreads();

    f16x8 ah[4], al[4], bh[4], bl[4];
#pragma unroll
    for (int i = 0; i < 4; i++) {
      const int ra = (wr + i * 16 + fr) * 32 + kg * 8;
      const int rb = (wc + i * 16 + fr) * 32 + kg * 8;
      ah[i] = *(const f16x8*)(const void*)(sAh + ra);
      al[i] = *(const f16x8*)(const void*)(sAl + ra);
      bh[i] = *(const f16x8*)(const void*)(sBh + rb);
      bl[i] = *(const f16x8*)(const void*)(sBl + rb);
    }
#pragma unroll
    for (int i = 0; i < 4; i++)
#pragma unroll
      for (int j = 0; j < 4; j++) {
        acc[i][j] = __builtin_amdgcn_mfma_f32_16x16x32_f16(ah[i], bh[j], acc[i][j], 0, 0, 0);
        acc[i][j] = __builtin_amdgcn_mfma_f32_16x16x32_f16(ah[i], bl[j], acc[i][j], 0, 0, 0);
        acc[i][j] = __builtin_amdgcn_mfma_f32_16x16x32_f16(al[i], bh[j], acc[i][j], 0, 0, 0);
      }
  }

  // epilogue: C row = (lane>>4)*4 + reg, col = lane&15  [verified m89/m91]
#pragma unroll
  for (int i = 0; i < 4; i++)
#pragma unroll
    for (int j = 0; j < 4; j++) {
      const int rowb = bm * 128 + wr + i * 16 + kg * 4;
      const int gcol = bn * 128 + wc + j * 16 + fr;
      const int colb = bn * 128 + wc + j * 16;
#pragma unroll
      for (int r = 0; r < 4; r++) {
        const int grow = rowb + r;
        const size_t o = (size_t)grow * N + gcol;
        if (EPI == 0) {
          const float v = acc[i][j][r] * ISCL2 + bias[gcol];
          const unsigned long long b1 = __ballot(v > TAUZ);
          const unsigned long long b2 = __ballot(fabsf(v) <= TAUZ);
          if (fr == 0) {
            const unsigned lo = (unsigned)((b1 >> (kg * 16)) & 0xFFFFull);
            const unsigned hi = (unsigned)((b2 >> (kg * 16)) & 0xFFFFull);
            wOut[(size_t)grow * (N >> 4) + (colb >> 4)] = lo | (hi << 16);
          }
          const float h = v > 0.f ? v : 0.f;
          unsigned short hh, hl;
          splitf(h, hh, hl);
          outH[o] = hh;
          outL[o] = hl;
        } else {  // EPI == 5: split-K fp32 partial
          outP[((size_t)kz * M + grow) * N + gcol] = acc[i][j][r] * ISCL2;
        }
      }
    }
}

// ---------------------------------------------------------------------------
// combine_y: out[i] = sum of 4 K-partials + bias[col] + x[i].  Vectorized ×4.
// ---------------------------------------------------------------------------
__global__ void combine_y(const float* __restrict__ P, const float* __restrict__ x,
                          const float* __restrict__ bias, int CBi,
                          float* __restrict__ out)
{
  const int i = blockIdx.x * blockDim.x + threadIdx.x;   // float4 index
  const int n4 = CBi * Ddim / 4;
  if (i >= n4) return;
  const size_t plane = (size_t)CBi * Ddim / 4;
  const float4 a = ((const float4*)P)[i];
  const float4 b = ((const float4*)P)[plane + i];
  const float4 c = ((const float4*)P)[2 * plane + i];
  const float4 d = ((const float4*)P)[3 * plane + i];
  const float4 xv = ((const float4*)x)[i];
  const int col = (i * 4) & (Ddim - 1);
  const float4 bv = *(const float4*)(bias + col);
  float4 o;
  o.x = a.x + b.x + c.x + d.x + bv.x + xv.x;
  o.y = a.y + b.y + c.y + d.y + bv.y + xv.y;
  o.z = a.z + b.z + c.z + d.z + bv.z + xv.z;
  o.w = a.w + b.w + c.w + d.w + bv.w + xv.w;
  ((float4*)out)[i] = o;
}

// ---------------------------------------------------------------------------
// Backward NT GEMM, single fp16 term. A [M,K] fp16 unscaled; B = WT hi (×SCL).
// Low arithmetic intensity (16 MFMA : 4 gload) -> 4 blocks/CU occupancy.
// EPI 2: v = C*ISCL * weight (decoded from 2-bit pack); store fp16.
// EPI 4: v = C*ISCL; store fp32 partial at plane kz (split-K).
// ---------------------------------------------------------------------------
template<int EPI>
__global__ __launch_bounds__(256, 4)
void gemm_b1(const unsigned short* __restrict__ A,
             const unsigned short* __restrict__ B,
             int M, int N, int K, int KP,
             const unsigned* __restrict__ wIn,
             unsigned short* __restrict__ outX,
             float* __restrict__ outP)
{
  __shared__ __align__(16) unsigned short smem[2 * 128 * 32];
  unsigned short* sA = smem;
  unsigned short* sB = smem + 4096;

  const unsigned gx = gridDim.x, gy = gridDim.y;
  const unsigned nwg = gx * gy * gridDim.z;
  unsigned lid = (blockIdx.z * gy + blockIdx.y) * gx + blockIdx.x;
  lid = xcd_swz(lid, nwg);
  const int bn = lid % gx;
  const int bm = (lid / gx) % gy;
  const int kz = lid / (gx * gy);

  const int t    = threadIdx.x;
  const int lane = t & 63;
  const int w    = t >> 6;
  const int wr   = (w >> 1) * 64;
  const int wc   = (w & 1) * 64;
  const int fr   = lane & 15;
  const int kg   = lane >> 4;

  f32x4 acc[4][4];
#pragma unroll
  for (int i = 0; i < 4; i++)
#pragma unroll
    for (int j = 0; j < 4; j++) acc[i][j] = (f32x4){0.f, 0.f, 0.f, 0.f};

  const int sr = t >> 2;
  const int sc = (t & 3) << 3;
  const size_t aRow  = (size_t)(bm * 128 + sr) * K;
  const size_t bRow  = (size_t)(bn * 128 + sr) * K;
  const size_t rowSk = (size_t)64 * K;
  const int ldsOff   = sr * 32 + sc;
  const int kbase    = kz * KP;

  for (int k0 = kbase; k0 < kbase + KP; k0 += 32) {
    __syncthreads();
    {
      const size_t ga = aRow + k0 + sc;
      const size_t gb = bRow + k0 + sc;
      gload_lds16(A + ga,         sA + ldsOff);
      gload_lds16(A + ga + rowSk, sA + 2048 + ldsOff);
      gload_lds16(B + gb,         sB + ldsOff);
      gload_lds16(B + gb + rowSk, sB + 2048 + ldsOff);
    }
    __syncthreads();

    f16x8 a[4], b[4];
#pragma unroll
    for (int i = 0; i < 4; i++) {
      a[i] = *(const f16x8*)(const void*)(sA + (wr + i * 16 + fr) * 32 + kg * 8);
      b[i] = *(const f16x8*)(const void*)(sB + (wc + i * 16 + fr) * 32 + kg * 8);
    }
#pragma unroll
    for (int i = 0; i < 4; i++)
#pragma unroll
      for (int j = 0; j < 4; j++)
        acc[i][j] = __builtin_amdgcn_mfma_f32_16x16x32_f16(a[i], b[j], acc[i][j], 0, 0, 0);
  }

#pragma unroll
  for (int i = 0; i < 4; i++)
#pragma unroll
    for (int j = 0; j < 4; j++) {
      const int rowb = bm * 128 + wr + i * 16 + kg * 4;
      const int gcol = bn * 128 + wc + j * 16 + fr;
#pragma unroll
      for (int r = 0; r < 4; r++) {
        const int grow = rowb + r;
        const size_t o = (size_t)grow * N + gcol;
        float v = acc[i][j][r] * ISCL;
        if (EPI == 2) {
          const unsigned word = wIn[(size_t)grow * (N >> 4) + (gcol >> 4)];
          const int bit = gcol & 15;
          const float wgt = ((word >> bit) & 1u) ? 1.f
                          : (((word >> (bit + 16)) & 1u) ? 0.5f : 0.f);
          v *= wgt;
          outX[o] = f2h(v);
        } else {  // EPI == 4: split-K fp32 partial
          outP[((size_t)kz * M + grow) * N + gcol] = v;
        }
      }
    }
}

// ---------------------------------------------------------------------------
// combine_ut: ut[row,col] = f2h(sum of 4 K-partials); fused per-row dot:
// tail[row] += coeff * sum_col(sum4 * u[row,col]).  One wave per row.
// ---------------------------------------------------------------------------
__global__ void combine_ut(const float* __restrict__ P, const float* __restrict__ u,
                           int CBi, unsigned short* __restrict__ ut,
                           float* __restrict__ tail, float coeff)
{
  const int row  = blockIdx.x * 4 + (threadIdx.x >> 6);
  const int lane = threadIdx.x & 63;
  const size_t rowoff = (size_t)row * Ddim + lane * 16;
  const size_t plane  = (size_t)CBi * Ddim;
  const float4* p0 = (const float4*)(P + rowoff);
  const float4* p1 = (const float4*)(P + plane + rowoff);
  const float4* p2 = (const float4*)(P + 2 * plane + rowoff);
  const float4* p3 = (const float4*)(P + 3 * plane + rowoff);
  const float4* ur = (const float4*)(u + rowoff);
  ushort4* uo = (ushort4*)(ut + rowoff);
  float dot = 0.f;
#pragma unroll
  for (int q = 0; q < 4; q++) {
    const float4 a = p0[q], b = p1[q], c = p2[q], d = p3[q];
    const float4 uu = ur[q];
    const float s0 = a.x + b.x + c.x + d.x;
    const float s1 = a.y + b.y + c.y + d.y;
    const float s2 = a.z + b.z + c.z + d.z;
    const float s3 = a.w + b.w + c.w + d.w;
    dot += s0 * uu.x + s1 * uu.y + s2 * uu.z + s3 * uu.w;
    ushort4 o;
    o.x = f2h(s0); o.y = f2h(s1); o.z = f2h(s2); o.w = f2h(s3);
    uo[q] = o;
  }
#pragma unroll
  for (int o = 32; o > 0; o >>= 1) dot += __shfl_down(dot, o);
  if (lane == 0) tail[row] += coeff * dot;
}

// ---------------------------------------------------------------------------
// W [R,C] fp32 -> Wh/Wl [R,C] split (×SCL) and WTh [C,R] hi (×SCL)
// ---------------------------------------------------------------------------
__global__ void split_transpose(const float* __restrict__ W, int R, int C,
                                unsigned short* __restrict__ Wh,
                                unsigned short* __restrict__ Wl,
                                unsigned short* __restrict__ WTh)
{
  __shared__ float tile[32][33];
  const int tx = threadIdx.x, ty = threadIdx.y;
  const int bx = blockIdx.x << 5, by = blockIdx.y << 5;
#pragma unroll
  for (int k = 0; k < 4; k++) {
    const int r = by + ty + k * 8;
    const size_t o = (size_t)r * C + bx + tx;
    const float v = W[o];
    tile[ty + k * 8][tx] = v;
    unsigned short h, l;
    splitf(v, h, l);
    Wh[o] = h;
    Wl[o] = l;
  }
  __syncthreads();
#pragma unroll
  for (int k = 0; k < 4; k++) {
    const int c = bx + ty + k * 8;
    const size_t o = (size_t)c * R + by + tx;
    const float v = tile[tx][ty + k * 8];
    unsigned short h, l;
    splitf(v, h, l);
    WTh[o] = h;
  }
}

// prep: x -> split (xh,xl);  u -> fp16 ut   (fused, one pass)
__global__ void prep_xu(const float* __restrict__ X, const float* __restrict__ U,
                        int n4,
                        unsigned short* __restrict__ Xh, unsigned short* __restrict__ Xl,
                        unsigned short* __restrict__ Ut)
{
  const int i = blockIdx.x * blockDim.x + threadIdx.x;
  if (i >= n4) return;
  const float4 v = ((const float4*)X)[i];
  ushort4 hv, lv;
  splitf(v.x, hv.x, lv.x);
  splitf(v.y, hv.y, lv.y);
  splitf(v.z, hv.z, lv.z);
  splitf(v.w, hv.w, lv.w);
  ((ushort4*)Xh)[i] = hv;
  ((ushort4*)Xl)[i] = lv;
  const float4 uv = ((const float4*)U)[i];
  ushort4 y;
  y.x = f2h(uv.x); y.y = f2h(uv.y); y.z = f2h(uv.z); y.w = f2h(uv.w);
  ((ushort4*)Ut)[i] = y;
}

__global__ void zero_tail(float* __restrict__ t)
{
  const int i = blockIdx.x * blockDim.x + threadIdx.x;
  if (i < Bdim) t[i] = 0.f;
}

// ---------------------------------------------------------------------------
extern "C" void kernel_launch(void* const* d_in, const int* in_sizes, int n_in,
                              void* d_out, int out_size, void* d_ws, size_t ws_size,
                              hipStream_t stream)
{
  (void)in_sizes; (void)n_in; (void)out_size;
  const float* x  = (const float*)d_in[0];
  const float* u  = (const float*)d_in[1];
  const float* W1 = (const float*)d_in[2];
  const float* b1 = (const float*)d_in[3];
  const float* W2 = (const float*)d_in[4];
  const float* b2 = (const float*)d_in[5];
  const float* W3 = (const float*)d_in[6];
  const float* b3 = (const float*)d_in[7];
  float* out = (float*)d_out;
  float* outTail = out + (size_t)Bdim * Ddim;

  const size_t HD = (size_t)Hdim * Ddim;
  const size_t HH = (size_t)Hdim * Hdim;

  // persistent: W1h/l/Th 24 + W2h/l/Th 96 + W3h/l/Th 24 = 144 MB
  const size_t persistent = 6 * (HD * 2) + 3 * (HH * 2) + 64 * 256;
  // per-row: xh/xl 4096 + ut 2048 + h1 16384 (alias: y-partials, dz2/dz1)
  //          + h2 16384 (alias: ut partials) + packed w1/w2 2048 = 40960
  const int cands[5] = {8192, 4096, 2048, 1024, 512};
  int CB = 512;
  for (int i = 0; i < 5; i++) {
    if (persistent + (size_t)cands[i] * 40960 + 8192 <= ws_size) { CB = cands[i]; break; }
  }

  char* ws = (char*)d_ws;
  size_t off = 0;
  auto carve = [&](size_t bytes) {
    void* p = ws + off;
    off += (bytes + 255) & ~(size_t)255;
    return p;
  };

  unsigned short* W1h  = (unsigned short*)carve(HD * 2);
  unsigned short* W1l  = (unsigned short*)carve(HD * 2);
  unsigned short* W1Th = (unsigned short*)carve(HD * 2);
  unsigned short* W2h  = (unsigned short*)carve(HH * 2);
  unsigned short* W2l  = (unsigned short*)carve(HH * 2);
  unsigned short* W2Th = (unsigned short*)carve(HH * 2);
  unsigned short* W3h  = (unsigned short*)carve(HD * 2);
  unsigned short* W3l  = (unsigned short*)carve(HD * 2);
  unsigned short* W3Th = (unsigned short*)carve(HD * 2);

  const size_t CD = (size_t)CB * Ddim;
  const size_t CH = (size_t)CB * Hdim;
  unsigned short* xh  = (unsigned short*)carve(CD * 2);
  unsigned short* xl  = (unsigned short*)carve(CD * 2);
  unsigned short* ut  = (unsigned short*)carve(CD * 2);
  unsigned short* h1h = (unsigned short*)carve(CH * 2);  // later y-partials, dz2
  unsigned short* h1l = (unsigned short*)carve(CH * 2);  // later y-partials, dz1
  unsigned short* h2h = (unsigned short*)carve(CH * 2);  // later ut partials
  unsigned short* h2l = (unsigned short*)carve(CH * 2);  //   (contiguous)
  unsigned* w1p = (unsigned*)carve(CH / 4);              // 2-bit packed weights
  unsigned* w2p = (unsigned*)carve(CH / 4);
  unsigned short* dz2 = h1h;            // alias: free after y-combine
  unsigned short* dz1 = h1l;
  float* Pyb  = (float*)h1h;            // y partials: 4 × [CB,1024] fp32 = CH*4 B
  float* Pbuf = (float*)h2h;            // ut partials: 4 × [CB,1024] fp32 = CH*4 B

  split_transpose<<<dim3(Ddim / 32, Hdim / 32), dim3(32, 8), 0, stream>>>(
      W1, Hdim, Ddim, W1h, W1l, W1Th);
  split_transpose<<<dim3(Hdim / 32, Hdim / 32), dim3(32, 8), 0, stream>>>(
      W2, Hdim, Hdim, W2h, W2l, W2Th);
  split_transpose<<<dim3(Hdim / 32, Ddim / 32), dim3(32, 8), 0, stream>>>(
      W3, Ddim, Hdim, W3h, W3l, W3Th);
  zero_tail<<<Bdim / 256, 256, 0, stream>>>(outTail);

  const float coeff[NPOW] = {1.f, -1.f / 2.f, 1.f / 3.f, -1.f / 4.f, 1.f / 5.f,
                             -1.f / 6.f, 1.f / 7.f, -1.f / 8.f, 1.f / 9.f, -1.f / 10.f};

  const int nChunk = Bdim / CB;
  for (int c = 0; c < nChunk; c++) {
    const size_t cb0 = (size_t)c * CB;
    const float* xc = x + cb0 * Ddim;
    const float* uc = u + cb0 * Ddim;
    const int n4 = (int)(CD / 4);

    prep_xu<<<n4 / 256, 256, 0, stream>>>(xc, uc, n4, xh, xl, ut);

    // ---- forward: z1/z2 via 3-term MFMA; packed hedge weights in epilogue ----
    gemm_f3<0><<<dim3(Hdim / 128, CB / 128), 256, 0, stream>>>(
        xh, xl, W1h, W1l, CB, Hdim, Ddim, Ddim, b1, w1p, nullptr, h1h, h1l);
    gemm_f3<0><<<dim3(Hdim / 128, CB / 128), 256, 0, stream>>>(
        h1h, h1l, W2h, W2l, CB, Hdim, Hdim, Hdim, b2, w2p, nullptr, h2h, h2l);

    // y = x + h2@W3^T + b3 via split-K (partials alias h1, dead after z2)
    gemm_f3<5><<<dim3(Ddim / 128, CB / 128, 4), 256, 0, stream>>>(
        h2h, h2l, W3h, W3l, CB, Ddim, Hdim, Hdim / 4, nullptr, nullptr,
        Pyb, nullptr, nullptr);
    combine_y<<<(n4 + 255) / 256, 256, 0, stream>>>(Pyb, xc, b3, CB,
                                                    out + cb0 * Ddim);

    // ---- Neumann series VJP loop (1-term fp16, packed hedge weights) ----
    for (int n = 0; n < NPOW; n++) {
      gemm_b1<2><<<dim3(Hdim / 128, CB / 128), 256, 0, stream>>>(
          ut, W3Th, CB, Hdim, Ddim, Ddim, w2p, dz2, nullptr);
      gemm_b1<2><<<dim3(Hdim / 128, CB / 128), 256, 0, stream>>>(
          dz2, W2Th, CB, Hdim, Hdim, Hdim, w1p, dz1, nullptr);
      // ut = dz1 @ W1 via split-K (4 × K=1024 planes, full-machine grid)
      gemm_b1<4><<<dim3(Ddim / 128, CB / 128, 4), 256, 0, stream>>>(
          dz1, W1Th, CB, Ddim, Hdim, Hdim / 4, nullptr, nullptr, Pbuf);
      // combine partials -> fp16 ut, fused logdet dot
      combine_ut<<<CB / 4, 256, 0, stream>>>(Pbuf, uc, CB, ut,
                                             outTail + cb0, coeff[n]);
    }
  }
}

// Round 18
// 7458.015 us; speedup vs baseline: 1.0079x; 1.0079x over previous
//
#include <hip/hip_runtime.h>
#include <hip/hip_bf16.h>

#define Bdim 8192
#define Ddim 1024
#define Hdim 4096
#define NPOW 10
#define TAUZ 1e-5f   // hedge band: |z| < TAUZ gets relu'-weight 0.5

// Scaled-fp16-split: split arrays store SCL*value as (hi,lo) fp16.
#define SCL   512.0f
#define ISCL  (1.0f / 512.0f)
#define ISCL2 (1.0f / (512.0f * 512.0f))

typedef _Float16 f16x8 __attribute__((ext_vector_type(8)));
typedef float f32x4 __attribute__((ext_vector_type(4)));

__device__ __forceinline__ float h2f(unsigned short b) {
  _Float16 h = __builtin_bit_cast(_Float16, b);
  return (float)h;
}
__device__ __forceinline__ unsigned short f2h(float v) {
  return __builtin_bit_cast(unsigned short, (_Float16)v);
}
__device__ __forceinline__ void splitf(float v, unsigned short& hi, unsigned short& lo) {
  const float s = v * SCL;
  const _Float16 h = (_Float16)s;
  const _Float16 l = (_Float16)(s - (float)h);
  hi = __builtin_bit_cast(unsigned short, h);
  lo = __builtin_bit_cast(unsigned short, l);
}

__device__ __forceinline__ void gload_lds16(const void* g, void* l) {
  __builtin_amdgcn_global_load_lds(
      (const __attribute__((address_space(1))) void*)g,
      (__attribute__((address_space(3))) void*)l, 16, 0, 0);
}

// ---------------------------------------------------------------------------
// Forward NT GEMM, split-fp16 3-term: C = sum_k A[m,k]*B[n,k] (×SCL² in acc).
// EPI 0 (z-pass):   v = C*ISCL2 + bias[n]; hedge weight 2-bit packed
//                   (u32 per 16 cols: lo16 = v>TAUZ, hi16 = |v|<=TAUZ);
//                   h = relu(v) stored split-fp16.  grid.z=1.
// EPI 5 (y-split-K): v = C*ISCL2 over K-range [z*KP,(z+1)*KP); fp32 partial.
// NOTE: no XCD swizzle — r17 measured it doubling FETCH (contiguous-per-XCD
// work ranges force the whole W-panel set through one 4MB L2).
// ---------------------------------------------------------------------------
template<int EPI>
__global__ __launch_bounds__(256, 2)
void gemm_f3(const unsigned short* __restrict__ Ah,
             const unsigned short* __restrict__ Al,
             const unsigned short* __restrict__ Bh,
             const unsigned short* __restrict__ Bl,
             int M, int N, int K, int KP,
             const float* __restrict__ bias,
             unsigned* __restrict__ wOut,
             float* __restrict__ outP,
             unsigned short* __restrict__ outH,
             unsigned short* __restrict__ outL)
{
  __shared__ __align__(16) unsigned short smem[4 * 128 * 32];
  unsigned short* sAh = smem;
  unsigned short* sAl = smem + 4096;
  unsigned short* sBh = smem + 8192;
  unsigned short* sBl = smem + 12288;

  const int t    = threadIdx.x;
  const int bn   = blockIdx.x;
  const int bm   = blockIdx.y;
  const int kz   = blockIdx.z;
  const int lane = t & 63;
  const int w    = t >> 6;
  const int wr   = (w >> 1) * 64;
  const int wc   = (w & 1) * 64;
  const int fr   = lane & 15;
  const int kg   = lane >> 4;

  f32x4 acc[4][4];
#pragma unroll
  for (int i = 0; i < 4; i++)
#pragma unroll
    for (int j = 0; j < 4; j++) acc[i][j] = (f32x4){0.f, 0.f, 0.f, 0.f};

  const int sr = t >> 2;
  const int sc = (t & 3) << 3;
  const size_t aRow  = (size_t)(bm * 128 + sr) * K;
  const size_t bRow  = (size_t)(bn * 128 + sr) * K;
  const size_t rowSk = (size_t)64 * K;
  const int ldsOff   = sr * 32 + sc;
  const int kbase    = kz * KP;

  for (int k0 = kbase; k0 < kbase + KP; k0 += 32) {
    __syncthreads();
    {
      const size_t ga = aRow + k0 + sc;
      const size_t gb = bRow + k0 + sc;
      gload_lds16(Ah + ga,         sAh + ldsOff);
      gload_lds16(Ah + ga + rowSk, sAh + 2048 + ldsOff);
      gload_lds16(Al + ga,         sAl + ldsOff);
      gload_lds16(Al + ga + rowSk, sAl + 2048 + ldsOff);
      gload_lds16(Bh + gb,         sBh + ldsOff);
      gload_lds16(Bh + gb + rowSk, sBh + 2048 + ldsOff);
      gload_lds16(Bl + gb,         sBl + ldsOff);
      gload_lds16(Bl + gb + rowSk, sBl + 2048 + ldsOff);
    }
    __syncthreads();

    f16x8 ah[4], al[4], bh[4], bl[4];
#pragma unroll
    for (int i = 0; i < 4; i++) {
      const int ra = (wr + i * 16 + fr) * 32 + kg * 8;
      const int rb = (wc + i * 16 + fr) * 32 + kg * 8;
      ah[i] = *(const f16x8*)(const void*)(sAh + ra);
      al[i] = *(const f16x8*)(const void*)(sAl + ra);
      bh[i] = *(const f16x8*)(const void*)(sBh + rb);
      bl[i] = *(const f16x8*)(const void*)(sBl + rb);
    }
#pragma unroll
    for (int i = 0; i < 4; i++)
#pragma unroll
      for (int j = 0; j < 4; j++) {
        acc[i][j] = __builtin_amdgcn_mfma_f32_16x16x32_f16(ah[i], bh[j], acc[i][j], 0, 0, 0);
        acc[i][j] = __builtin_amdgcn_mfma_f32_16x16x32_f16(ah[i], bl[j], acc[i][j], 0, 0, 0);
        acc[i][j] = __builtin_amdgcn_mfma_f32_16x16x32_f16(al[i], bh[j], acc[i][j], 0, 0, 0);
      }
  }

  // epilogue: C row = (lane>>4)*4 + reg, col = lane&15  [verified m89/m91]
#pragma unroll
  for (int i = 0; i < 4; i++)
#pragma unroll
    for (int j = 0; j < 4; j++) {
      const int rowb = bm * 128 + wr + i * 16 + kg * 4;
      const int gcol = bn * 128 + wc + j * 16 + fr;
      const int colb = bn * 128 + wc + j * 16;
#pragma unroll
      for (int r = 0; r < 4; r++) {
        const int grow = rowb + r;
        const size_t o = (size_t)grow * N + gcol;
        if (EPI == 0) {
          const float v = acc[i][j][r] * ISCL2 + bias[gcol];
          const unsigned long long b1 = __ballot(v > TAUZ);
          const unsigned long long b2 = __ballot(fabsf(v) <= TAUZ);
          if (fr == 0) {
            const unsigned lo = (unsigned)((b1 >> (kg * 16)) & 0xFFFFull);
            const unsigned hi = (unsigned)((b2 >> (kg * 16)) & 0xFFFFull);
            wOut[(size_t)grow * (N >> 4) + (colb >> 4)] = lo | (hi << 16);
          }
          const float h = v > 0.f ? v : 0.f;
          unsigned short hh, hl;
          splitf(h, hh, hl);
          outH[o] = hh;
          outL[o] = hl;
        } else {  // EPI == 5: split-K fp32 partial
          outP[((size_t)kz * M + grow) * N + gcol] = acc[i][j][r] * ISCL2;
        }
      }
    }
}

// ---------------------------------------------------------------------------
// combine_y: out[i] = sum of 4 K-partials + bias[col] + x[i].  Vectorized ×4.
// ---------------------------------------------------------------------------
__global__ void combine_y(const float* __restrict__ P, const float* __restrict__ x,
                          const float* __restrict__ bias, int CBi,
                          float* __restrict__ out)
{
  const int i = blockIdx.x * blockDim.x + threadIdx.x;   // float4 index
  const int n4 = CBi * Ddim / 4;
  if (i >= n4) return;
  const size_t plane = (size_t)CBi * Ddim / 4;
  const float4 a = ((const float4*)P)[i];
  const float4 b = ((const float4*)P)[plane + i];
  const float4 c = ((const float4*)P)[2 * plane + i];
  const float4 d = ((const float4*)P)[3 * plane + i];
  const float4 xv = ((const float4*)x)[i];
  const int col = (i * 4) & (Ddim - 1);
  const float4 bv = *(const float4*)(bias + col);
  float4 o;
  o.x = a.x + b.x + c.x + d.x + bv.x + xv.x;
  o.y = a.y + b.y + c.y + d.y + bv.y + xv.y;
  o.z = a.z + b.z + c.z + d.z + bv.z + xv.z;
  o.w = a.w + b.w + c.w + d.w + bv.w + xv.w;
  ((float4*)out)[i] = o;
}

// ---------------------------------------------------------------------------
// Backward NT GEMM, single fp16 term. A [M,K] fp16 unscaled; B = WT hi (×SCL).
// Low arithmetic intensity (16 MFMA : 4 gload) -> 4 blocks/CU occupancy.
// EPI 2: v = C*ISCL * weight (decoded from 2-bit pack); store fp16.
// EPI 4: v = C*ISCL; store fp32 partial at plane kz (split-K).
// ---------------------------------------------------------------------------
template<int EPI>
__global__ __launch_bounds__(256, 4)
void gemm_b1(const unsigned short* __restrict__ A,
             const unsigned short* __restrict__ B,
             int M, int N, int K, int KP,
             const unsigned* __restrict__ wIn,
             unsigned short* __restrict__ outX,
             float* __restrict__ outP)
{
  __shared__ __align__(16) unsigned short smem[2 * 128 * 32];
  unsigned short* sA = smem;
  unsigned short* sB = smem + 4096;

  const int t    = threadIdx.x;
  const int bn   = blockIdx.x;
  const int bm   = blockIdx.y;
  const int kz   = blockIdx.z;
  const int lane = t & 63;
  const int w    = t >> 6;
  const int wr   = (w >> 1) * 64;
  const int wc   = (w & 1) * 64;
  const int fr   = lane & 15;
  const int kg   = lane >> 4;

  f32x4 acc[4][4];
#pragma unroll
  for (int i = 0; i < 4; i++)
#pragma unroll
    for (int j = 0; j < 4; j++) acc[i][j] = (f32x4){0.f, 0.f, 0.f, 0.f};

  const int sr = t >> 2;
  const int sc = (t & 3) << 3;
  const size_t aRow  = (size_t)(bm * 128 + sr) * K;
  const size_t bRow  = (size_t)(bn * 128 + sr) * K;
  const size_t rowSk = (size_t)64 * K;
  const int ldsOff   = sr * 32 + sc;
  const int kbase    = kz * KP;

  for (int k0 = kbase; k0 < kbase + KP; k0 += 32) {
    __syncthreads();
    {
      const size_t ga = aRow + k0 + sc;
      const size_t gb = bRow + k0 + sc;
      gload_lds16(A + ga,         sA + ldsOff);
      gload_lds16(A + ga + rowSk, sA + 2048 + ldsOff);
      gload_lds16(B + gb,         sB + ldsOff);
      gload_lds16(B + gb + rowSk, sB + 2048 + ldsOff);
    }
    __syncthreads();

    f16x8 a[4], b[4];
#pragma unroll
    for (int i = 0; i < 4; i++) {
      a[i] = *(const f16x8*)(const void*)(sA + (wr + i * 16 + fr) * 32 + kg * 8);
      b[i] = *(const f16x8*)(const void*)(sB + (wc + i * 16 + fr) * 32 + kg * 8);
    }
#pragma unroll
    for (int i = 0; i < 4; i++)
#pragma unroll
      for (int j = 0; j < 4; j++)
        acc[i][j] = __builtin_amdgcn_mfma_f32_16x16x32_f16(a[i], b[j], acc[i][j], 0, 0, 0);
  }

#pragma unroll
  for (int i = 0; i < 4; i++)
#pragma unroll
    for (int j = 0; j < 4; j++) {
      const int rowb = bm * 128 + wr + i * 16 + kg * 4;
      const int gcol = bn * 128 + wc + j * 16 + fr;
#pragma unroll
      for (int r = 0; r < 4; r++) {
        const int grow = rowb + r;
        const size_t o = (size_t)grow * N + gcol;
        float v = acc[i][j][r] * ISCL;
        if (EPI == 2) {
          const unsigned word = wIn[(size_t)grow * (N >> 4) + (gcol >> 4)];
          const int bit = gcol & 15;
          const float wgt = ((word >> bit) & 1u) ? 1.f
                          : (((word >> (bit + 16)) & 1u) ? 0.5f : 0.f);
          v *= wgt;
          outX[o] = f2h(v);
        } else {  // EPI == 4: split-K fp32 partial
          outP[((size_t)kz * M + grow) * N + gcol] = v;
        }
      }
    }
}

// ---------------------------------------------------------------------------
// combine_ut: ut[row,col] = f2h(sum of 4 K-partials); fused per-row dot:
// tail[row] += coeff * sum_col(sum4 * u[row,col]).  One wave per row.
// ---------------------------------------------------------------------------
__global__ void combine_ut(const float* __restrict__ P, const float* __restrict__ u,
                           int CBi, unsigned short* __restrict__ ut,
                           float* __restrict__ tail, float coeff)
{
  const int row  = blockIdx.x * 4 + (threadIdx.x >> 6);
  const int lane = threadIdx.x & 63;
  const size_t rowoff = (size_t)row * Ddim + lane * 16;
  const size_t plane  = (size_t)CBi * Ddim;
  const float4* p0 = (const float4*)(P + rowoff);
  const float4* p1 = (const float4*)(P + plane + rowoff);
  const float4* p2 = (const float4*)(P + 2 * plane + rowoff);
  const float4* p3 = (const float4*)(P + 3 * plane + rowoff);
  const float4* ur = (const float4*)(u + rowoff);
  ushort4* uo = (ushort4*)(ut + rowoff);
  float dot = 0.f;
#pragma unroll
  for (int q = 0; q < 4; q++) {
    const float4 a = p0[q], b = p1[q], c = p2[q], d = p3[q];
    const float4 uu = ur[q];
    const float s0 = a.x + b.x + c.x + d.x;
    const float s1 = a.y + b.y + c.y + d.y;
    const float s2 = a.z + b.z + c.z + d.z;
    const float s3 = a.w + b.w + c.w + d.w;
    dot += s0 * uu.x + s1 * uu.y + s2 * uu.z + s3 * uu.w;
    ushort4 o;
    o.x = f2h(s0); o.y = f2h(s1); o.z = f2h(s2); o.w = f2h(s3);
    uo[q] = o;
  }
#pragma unroll
  for (int o = 32; o > 0; o >>= 1) dot += __shfl_down(dot, o);
  if (lane == 0) tail[row] += coeff * dot;
}

// ---------------------------------------------------------------------------
// W [R,C] fp32 -> Wh/Wl [R,C] split (×SCL) and WTh [C,R] hi (×SCL)
// ---------------------------------------------------------------------------
__global__ void split_transpose(const float* __restrict__ W, int R, int C,
                                unsigned short* __restrict__ Wh,
                                unsigned short* __restrict__ Wl,
                                unsigned short* __restrict__ WTh)
{
  __shared__ float tile[32][33];
  const int tx = threadIdx.x, ty = threadIdx.y;
  const int bx = blockIdx.x << 5, by = blockIdx.y << 5;
#pragma unroll
  for (int k = 0; k < 4; k++) {
    const int r = by + ty + k * 8;
    const size_t o = (size_t)r * C + bx + tx;
    const float v = W[o];
    tile[ty + k * 8][tx] = v;
    unsigned short h, l;
    splitf(v, h, l);
    Wh[o] = h;
    Wl[o] = l;
  }
  __syncthreads();
#pragma unroll
  for (int k = 0; k < 4; k++) {
    const int c = bx + ty + k * 8;
    const size_t o = (size_t)c * R + by + tx;
    const float v = tile[tx][ty + k * 8];
    unsigned short h, l;
    splitf(v, h, l);
    WTh[o] = h;
  }
}

// prep: x -> split (xh,xl);  u -> fp16 ut   (fused, one pass)
__global__ void prep_xu(const float* __restrict__ X, const float* __restrict__ U,
                        int n4,
                        unsigned short* __restrict__ Xh, unsigned short* __restrict__ Xl,
                        unsigned short* __restrict__ Ut)
{
  const int i = blockIdx.x * blockDim.x + threadIdx.x;
  if (i >= n4) return;
  const float4 v = ((const float4*)X)[i];
  ushort4 hv, lv;
  splitf(v.x, hv.x, lv.x);
  splitf(v.y, hv.y, lv.y);
  splitf(v.z, hv.z, lv.z);
  splitf(v.w, hv.w, lv.w);
  ((ushort4*)Xh)[i] = hv;
  ((ushort4*)Xl)[i] = lv;
  const float4 uv = ((const float4*)U)[i];
  ushort4 y;
  y.x = f2h(uv.x); y.y = f2h(uv.y); y.z = f2h(uv.z); y.w = f2h(uv.w);
  ((ushort4*)Ut)[i] = y;
}

__global__ void zero_tail(float* __restrict__ t)
{
  const int i = blockIdx.x * blockDim.x + threadIdx.x;
  if (i < Bdim) t[i] = 0.f;
}

// ---------------------------------------------------------------------------
extern "C" void kernel_launch(void* const* d_in, const int* in_sizes, int n_in,
                              void* d_out, int out_size, void* d_ws, size_t ws_size,
                              hipStream_t stream)
{
  (void)in_sizes; (void)n_in; (void)out_size;
  const float* x  = (const float*)d_in[0];
  const float* u  = (const float*)d_in[1];
  const float* W1 = (const float*)d_in[2];
  const float* b1 = (const float*)d_in[3];
  const float* W2 = (const float*)d_in[4];
  const float* b2 = (const float*)d_in[5];
  const float* W3 = (const float*)d_in[6];
  const float* b3 = (const float*)d_in[7];
  float* out = (float*)d_out;
  float* outTail = out + (size_t)Bdim * Ddim;

  const size_t HD = (size_t)Hdim * Ddim;
  const size_t HH = (size_t)Hdim * Hdim;

  // persistent: W1h/l/Th 24 + W2h/l/Th 96 + W3h/l/Th 24 = 144 MB
  const size_t persistent = 6 * (HD * 2) + 3 * (HH * 2) + 64 * 256;
  // per-row: xh/xl 4096 + ut 2048 + h1 16384 (alias: y-partials, dz2/dz1)
  //          + h2 16384 (alias: ut partials) + packed w1/w2 2048 = 40960
  const int cands[5] = {8192, 4096, 2048, 1024, 512};
  int CB = 512;
  for (int i = 0; i < 5; i++) {
    if (persistent + (size_t)cands[i] * 40960 + 8192 <= ws_size) { CB = cands[i]; break; }
  }

  char* ws = (char*)d_ws;
  size_t off = 0;
  auto carve = [&](size_t bytes) {
    void* p = ws + off;
    off += (bytes + 255) & ~(size_t)255;
    return p;
  };

  unsigned short* W1h  = (unsigned short*)carve(HD * 2);
  unsigned short* W1l  = (unsigned short*)carve(HD * 2);
  unsigned short* W1Th = (unsigned short*)carve(HD * 2);
  unsigned short* W2h  = (unsigned short*)carve(HH * 2);
  unsigned short* W2l  = (unsigned short*)carve(HH * 2);
  unsigned short* W2Th = (unsigned short*)carve(HH * 2);
  unsigned short* W3h  = (unsigned short*)carve(HD * 2);
  unsigned short* W3l  = (unsigned short*)carve(HD * 2);
  unsigned short* W3Th = (unsigned short*)carve(HD * 2);

  const size_t CD = (size_t)CB * Ddim;
  const size_t CH = (size_t)CB * Hdim;
  unsigned short* xh  = (unsigned short*)carve(CD * 2);
  unsigned short* xl  = (unsigned short*)carve(CD * 2);
  unsigned short* ut  = (unsigned short*)carve(CD * 2);
  unsigned short* h1h = (unsigned short*)carve(CH * 2);  // later y-partials, dz2
  unsigned short* h1l = (unsigned short*)carve(CH * 2);  // later y-partials, dz1
  unsigned short* h2h = (unsigned short*)carve(CH * 2);  // later ut partials
  unsigned short* h2l = (unsigned short*)carve(CH * 2);  //   (contiguous)
  unsigned* w1p = (unsigned*)carve(CH / 4);              // 2-bit packed weights
  unsigned* w2p = (unsigned*)carve(CH / 4);
  unsigned short* dz2 = h1h;            // alias: free after y-combine
  unsigned short* dz1 = h1l;
  float* Pyb  = (float*)h1h;            // y partials: 4 × [CB,1024] fp32 = CH*4 B
  float* Pbuf = (float*)h2h;            // ut partials: 4 × [CB,1024] fp32 = CH*4 B

  split_transpose<<<dim3(Ddim / 32, Hdim / 32), dim3(32, 8), 0, stream>>>(
      W1, Hdim, Ddim, W1h, W1l, W1Th);
  split_transpose<<<dim3(Hdim / 32, Hdim / 32), dim3(32, 8), 0, stream>>>(
      W2, Hdim, Hdim, W2h, W2l, W2Th);
  split_transpose<<<dim3(Hdim / 32, Ddim / 32), dim3(32, 8), 0, stream>>>(
      W3, Ddim, Hdim, W3h, W3l, W3Th);
  zero_tail<<<Bdim / 256, 256, 0, stream>>>(outTail);

  const float coeff[NPOW] = {1.f, -1.f / 2.f, 1.f / 3.f, -1.f / 4.f, 1.f / 5.f,
                             -1.f / 6.f, 1.f / 7.f, -1.f / 8.f, 1.f / 9.f, -1.f / 10.f};

  const int nChunk = Bdim / CB;
  for (int c = 0; c < nChunk; c++) {
    const size_t cb0 = (size_t)c * CB;
    const float* xc = x + cb0 * Ddim;
    const float* uc = u + cb0 * Ddim;
    const int n4 = (int)(CD / 4);

    prep_xu<<<n4 / 256, 256, 0, stream>>>(xc, uc, n4, xh, xl, ut);

    // ---- forward: z1/z2 via 3-term MFMA; packed hedge weights in epilogue ----
    gemm_f3<0><<<dim3(Hdim / 128, CB / 128), 256, 0, stream>>>(
        xh, xl, W1h, W1l, CB, Hdim, Ddim, Ddim, b1, w1p, nullptr, h1h, h1l);
    gemm_f3<0><<<dim3(Hdim / 128, CB / 128), 256, 0, stream>>>(
        h1h, h1l, W2h, W2l, CB, Hdim, Hdim, Hdim, b2, w2p, nullptr, h2h, h2l);

    // y = x + h2@W3^T + b3 via split-K (partials alias h1, dead after z2)
    gemm_f3<5><<<dim3(Ddim / 128, CB / 128, 4), 256, 0, stream>>>(
        h2h, h2l, W3h, W3l, CB, Ddim, Hdim, Hdim / 4, nullptr, nullptr,
        Pyb, nullptr, nullptr);
    combine_y<<<(n4 + 255) / 256, 256, 0, stream>>>(Pyb, xc, b3, CB,
                                                    out + cb0 * Ddim);

    // ---- Neumann series VJP loop (1-term fp16, packed hedge weights) ----
    for (int n = 0; n < NPOW; n++) {
      gemm_b1<2><<<dim3(Hdim / 128, CB / 128), 256, 0, stream>>>(
          ut, W3Th, CB, Hdim, Ddim, Ddim, w2p, dz2, nullptr);
      gemm_b1<2><<<dim3(Hdim / 128, CB / 128), 256, 0, stream>>>(
          dz2, W2Th, CB, Hdim, Hdim, Hdim, w1p, dz1, nullptr);
      // ut = dz1 @ W1 via split-K (4 × K=1024 planes, full-machine grid)
      gemm_b1<4><<<dim3(Ddim / 128, CB / 128, 4), 256, 0, stream>>>(
          dz1, W1Th, CB, Ddim, Hdim, Hdim / 4, nullptr, nullptr, Pbuf);
      // combine partials -> fp16 ut, fused logdet dot
      combine_ut<<<CB / 4, 256, 0, stream>>>(Pbuf, uc, CB, ut,
                                             outTail + cb0, coeff[n]);
    }
  }
}